// Round 11
// baseline (137.088 us; speedup 1.0000x reference)
//
#include <hip/hip_runtime.h>
#include <hip/hip_bf16.h>

#define NHEAD 4
#define DIN 128
#define DOUT 128

typedef __attribute__((ext_vector_type(8))) short bf16x8;
typedef __attribute__((ext_vector_type(4))) float f32x4;

__device__ __forceinline__ short bfb(float f) {
    __hip_bfloat16 h = __float2bfloat16(f);
    return *reinterpret_cast<short*>(&h);
}
__device__ __forceinline__ float2 bfpair(unsigned int u) {
    float2 r;
    r.x = __uint_as_float(u << 16);
    r.y = __uint_as_float(u & 0xFFFF0000u);
    return r;
}
__device__ __forceinline__ unsigned int pk2(float lo, float hi) {
    return (unsigned int)(unsigned short)bfb(lo) |
           ((unsigned int)(unsigned short)bfb(hi) << 16);
}
__device__ __forceinline__ bf16x8 cvt8r(float4 a, float4 b) {
    bf16x8 r;
    r[0] = bfb(a.x); r[1] = bfb(a.y); r[2] = bfb(a.z); r[3] = bfb(a.w);
    r[4] = bfb(b.x); r[5] = bfb(b.y); r[6] = bfb(b.z); r[7] = bfb(b.w);
    return r;
}

// ---------------- KP: W -> bf16 (tiny) ----------------
__global__ __launch_bounds__(256) void kprep_w(
    const float* __restrict__ W0, const float* __restrict__ W1,
    uint4* __restrict__ Wbf)
{
    const int i = blockIdx.x * 256 + threadIdx.x;
    const int nW8 = (2 * DOUT * DIN) / 8;     // 4096
    if (i >= nW8) return;
    const float* s = (i < nW8 / 2) ? (W0 + (size_t)i * 8)
                                   : (W1 + (size_t)(i - nW8 / 2) * 8);
    float4 a = ((const float4*)s)[0];
    float4 b = ((const float4*)s)[1];
    Wbf[i] = make_uint4(pk2(a.x, a.y), pk2(a.z, a.w),
                        pk2(b.x, b.y), pk2(b.z, b.w));
}

// ---------------- K1 tile compute (4 tiles from one LDS half) ----------------
__device__ __forceinline__ void k1_tiles(
    const uint4* __restrict__ ldsbuf, int nodebase, int n,
    int col, int rg, bool selfhalf, int hd,
    const bf16x8 (&afr)[2][4],
    const float4 (&bias4)[2], const float4 (&att4)[2],
    const float4 (&sc4)[2], const float4 (&of4)[2],
    unsigned short* __restrict__ nsbuf, unsigned short* __restrict__ h_neigh,
    float* __restrict__ att_self, float* __restrict__ att_neigh)
{
    for (int tt = 0; tt < 4; tt++) {
        const int nl = tt * 16 + col;
        bf16x8 bfr[4];
        #pragma unroll
        for (int kk = 0; kk < 4; kk++) {
            uint4 u = ldsbuf[nl * 16 + ((kk * 4 + rg) ^ (col & 7))];
            *(uint4*)&bfr[kk] = u;
        }

        f32x4 acc[2] = {{0.f,0.f,0.f,0.f},{0.f,0.f,0.f,0.f}};
        #pragma unroll
        for (int kk = 0; kk < 4; kk++) {
            acc[0] = __builtin_amdgcn_mfma_f32_16x16x32_bf16(afr[0][kk], bfr[kk], acc[0], 0, 0, 0);
            acc[1] = __builtin_amdgcn_mfma_f32_16x16x32_bf16(afr[1][kk], bfr[kk], acc[1], 0, 0, 0);
        }

        const int node = nodebase + tt * 16 + col;
        const bool valid = node < n;

        float v[2][4];
        float p = 0.f;
        #pragma unroll
        for (int ct = 0; ct < 2; ct++) {
            v[ct][0] = fmaxf(acc[ct][0] + bias4[ct].x, 0.f);
            v[ct][1] = fmaxf(acc[ct][1] + bias4[ct].y, 0.f);
            v[ct][2] = fmaxf(acc[ct][2] + bias4[ct].z, 0.f);
            v[ct][3] = fmaxf(acc[ct][3] + bias4[ct].w, 0.f);
            p += v[ct][0] * att4[ct].x + v[ct][1] * att4[ct].y
               + v[ct][2] * att4[ct].z + v[ct][3] * att4[ct].w;
        }
        p += __shfl_xor(p, 16);
        p += __shfl_xor(p, 32);

        if (selfhalf) {
            float s = v[0][0]+v[0][1]+v[0][2]+v[0][3]+v[1][0]+v[1][1]+v[1][2]+v[1][3];
            s += __shfl_xor(s, 16);
            s += __shfl_xor(s, 32);
            float m = s * (1.f / 32.f);
            float q = 0.f;
            #pragma unroll
            for (int ct = 0; ct < 2; ct++)
                #pragma unroll
                for (int j = 0; j < 4; j++) { float d = v[ct][j] - m; q += d * d; }
            q += __shfl_xor(q, 16);
            q += __shfl_xor(q, 32);
            float r = rsqrtf(q * (1.f / 32.f) + 1e-9f);
            #pragma unroll
            for (int ct = 0; ct < 2; ct++) {
                float n0 = 0.5f * ((v[ct][0] - m) * sc4[ct].x * r + of4[ct].x);
                float n1 = 0.5f * ((v[ct][1] - m) * sc4[ct].y * r + of4[ct].y);
                float n2 = 0.5f * ((v[ct][2] - m) * sc4[ct].z * r + of4[ct].z);
                float n3 = 0.5f * ((v[ct][3] - m) * sc4[ct].w * r + of4[ct].w);
                ushort4 st;
                st.x = (unsigned short)bfb(n0); st.y = (unsigned short)bfb(n1);
                st.z = (unsigned short)bfb(n2); st.w = (unsigned short)bfb(n3);
                if (valid)
                    *(ushort4*)(nsbuf + (size_t)node * DOUT + hd * 32 + ct * 16 + rg * 4) = st;
            }
            if (rg == 0 && valid)
                att_self[(size_t)node * NHEAD + hd] = p > 0.f ? p : 0.2f * p;
        } else {
            #pragma unroll
            for (int ct = 0; ct < 2; ct++) {
                ushort4 st;
                st.x = (unsigned short)bfb(v[ct][0]); st.y = (unsigned short)bfb(v[ct][1]);
                st.z = (unsigned short)bfb(v[ct][2]); st.w = (unsigned short)bfb(v[ct][3]);
                if (valid)
                    *(ushort4*)(h_neigh + (size_t)node * DOUT + hd * 32 + ct * 16 + rg * 4) = st;
            }
            if (rg == 0 && valid)
                att_neigh[(size_t)node * NHEAD + hd] = p > 0.f ? p : 0.2f * p;
        }
    }
}

// ---------------- K1: double-buffered staging + MFMA dual projection ----------------
// 512 threads = 8 waves; wave w: w<4 -> self half (nsbuf = 0.5*LN(h_self) + att_self),
// w>=4 -> h_neigh + att_neigh. NPB=128 in two 64-node halves: half-1 global loads
// issued BEFORE half-0 compute (T14 async-stage split) so HBM latency hides.
#define NPB 128

__global__ __launch_bounds__(512) void k1_mfma(
    const float* __restrict__ feat,
    const uint4* __restrict__ Wbf,
    const float* __restrict__ b0, const float* __restrict__ b1,
    const float* __restrict__ att, const float* __restrict__ scale,
    const float* __restrict__ offset,
    unsigned short* __restrict__ nsbuf, unsigned short* __restrict__ h_neigh,
    float* __restrict__ att_self, float* __restrict__ att_neigh, int n)
{
    __shared__ uint4 lds[2][64 * 16];      // 2 x 16 KB
    const int t = threadIdx.x;
    const int w = t >> 6;
    const int lane = t & 63;
    const int col = lane & 15;
    const int rg = lane >> 4;
    const bool selfhalf = (w < 4);
    const int hd = w & 3;

    bf16x8 afr[2][4];
    #pragma unroll
    for (int ct = 0; ct < 2; ct++) {
        const uint4* wr = Wbf + (size_t)(w * 32 + ct * 16 + col) * 16;
        #pragma unroll
        for (int kk = 0; kk < 4; kk++) {
            uint4 u = wr[kk * 4 + rg];
            *(uint4*)&afr[ct][kk] = u;
        }
    }
    float4 bias4[2], att4[2], sc4[2], of4[2];
    #pragma unroll
    for (int ct = 0; ct < 2; ct++) {
        int chg = w * 32 + ct * 16 + rg * 4;
        int chm = chg & 127;
        bias4[ct] = *(const float4*)((selfhalf ? b0 : b1) + chm);
        att4[ct]  = *(const float4*)(att + chg);
        sc4[ct]   = *(const float4*)(scale + 128 + chm);
        of4[ct]   = *(const float4*)(offset + 128 + chm);
    }

    const int base = blockIdx.x * NPB;

    // ---- stage half 0: load -> cvt -> LDS ----
    float4 ra[2][2];
    #pragma unroll
    for (int j = 0; j < 2; j++) {
        int li = j * 512 + t;
        int nl = li >> 4, sl = li & 15;
        int ng = base + nl; if (ng >= n) ng = n - 1;
        const float* p = feat + (size_t)ng * DIN + (sl ^ (nl & 7)) * 8;
        ra[j][0] = *(const float4*)p;
        ra[j][1] = *(const float4*)(p + 4);
    }
    #pragma unroll
    for (int j = 0; j < 2; j++) {
        bf16x8 v = cvt8r(ra[j][0], ra[j][1]);
        lds[0][j * 512 + t] = *(uint4*)&v;
    }

    // ---- issue half-1 loads early (latency hides under half-0 compute) ----
    float4 rb[2][2];
    #pragma unroll
    for (int j = 0; j < 2; j++) {
        int li = j * 512 + t;
        int nl = li >> 4, sl = li & 15;
        int ng = base + 64 + nl; if (ng >= n) ng = n - 1;
        const float* p = feat + (size_t)ng * DIN + (sl ^ (nl & 7)) * 8;
        rb[j][0] = *(const float4*)p;
        rb[j][1] = *(const float4*)(p + 4);
    }

    __syncthreads();   // LDS half 0 ready

    k1_tiles(lds[0], base, n, col, rg, selfhalf, hd, afr, bias4, att4, sc4, of4,
             nsbuf, h_neigh, att_self, att_neigh);

    // ---- write half 1 ----
    #pragma unroll
    for (int j = 0; j < 2; j++) {
        bf16x8 v = cvt8r(rb[j][0], rb[j][1]);
        lds[1][j * 512 + t] = *(uint4*)&v;
    }
    __syncthreads();   // LDS half 1 ready

    k1_tiles(lds[1], base + 64, n, col, rg, selfhalf, hd, afr, bias4, att4, sc4, of4,
             nsbuf, h_neigh, att_self, att_neigh);
}

// ---------------- K3: rowptr-search + softmax + aggregate + agg LN + combine --------
// 256 threads = 16 nodes/block, 16 lanes/node, 8 channels/thread (uint4 gather).
// 2-deep pipeline. Rowptr found in-block via 17-lane binary search on sorted erow.
__device__ __forceinline__ float group4_sum(float v) {
    v += __shfl_xor(v, 1);
    v += __shfl_xor(v, 2);
    return v;
}

__global__ __launch_bounds__(256) void k3_agg(
    const int* __restrict__ erow, const int* __restrict__ ecol,
    const float* __restrict__ eval,
    const float* __restrict__ att_self, const float* __restrict__ att_neigh,
    const unsigned short* __restrict__ nsbuf, const unsigned short* __restrict__ h_neigh,
    const float* __restrict__ scale, const float* __restrict__ offset,
    float* __restrict__ out, int n_nodes, int E)
{
    __shared__ int sptr[17];
    const int t = threadIdx.x;
    if (t < 17) {
        int nn = blockIdx.x * 16 + t;
        if (nn > n_nodes) nn = n_nodes;
        int lo = 0, hi = E;
        while (lo < hi) { int mid = (lo + hi) >> 1; if (erow[mid] < nn) lo = mid + 1; else hi = mid; }
        sptr[t] = lo;
    }
    __syncthreads();

    const int g = t >> 4;
    const int lane = t & 15;
    const int nid = blockIdx.x * 16 + g;
    if (nid >= n_nodes) return;
    const int head = lane >> 2;
    const int c8 = lane * 8;

    const int start = sptr[g], end = sptr[g + 1];
    const float as = att_self[(size_t)nid * NHEAD + head];

    float acc[8];
    #pragma unroll
    for (int j = 0; j < 8; j++) acc[j] = 0.f;
    float sumw = 0.f;

    float evA[4], anA[4];
    uint4 hvA[4];
    int cB[4];
    {
        int cA[4];
        #pragma unroll
        for (int i = 0; i < 4; i++) cA[i] = (start + i     < end) ? ecol[start + i]     : 0;
        #pragma unroll
        for (int i = 0; i < 4; i++) cB[i] = (start + 4 + i < end) ? ecol[start + 4 + i] : 0;
        #pragma unroll
        for (int i = 0; i < 4; i++) {
            evA[i] = (start + i < end) ? eval[start + i] : 0.f;
            anA[i] = att_neigh[(size_t)cA[i] * NHEAD + head];
            hvA[i] = *(const uint4*)(h_neigh + (size_t)cA[i] * DOUT + c8);
        }
    }

    for (int e = start; e < end; e += 4) {
        float evB[4], anB[4];
        uint4 hvB[4];
        #pragma unroll
        for (int i = 0; i < 4; i++) {
            evB[i] = (e + 4 + i < end) ? eval[e + 4 + i] : 0.f;
            anB[i] = att_neigh[(size_t)cB[i] * NHEAD + head];
            hvB[i] = *(const uint4*)(h_neigh + (size_t)cB[i] * DOUT + c8);
        }
        int cC[4];
        #pragma unroll
        for (int i = 0; i < 4; i++)
            cC[i] = (e + 8 + i < end) ? ecol[e + 8 + i] : 0;

        #pragma unroll
        for (int i = 0; i < 4; i++) {
            float wh = __expf(as + anA[i]) * evA[i];
            sumw += wh;
            float2 p;
            p = bfpair(hvA[i].x); acc[0] = fmaf(wh, p.x, acc[0]); acc[1] = fmaf(wh, p.y, acc[1]);
            p = bfpair(hvA[i].y); acc[2] = fmaf(wh, p.x, acc[2]); acc[3] = fmaf(wh, p.y, acc[3]);
            p = bfpair(hvA[i].z); acc[4] = fmaf(wh, p.x, acc[4]); acc[5] = fmaf(wh, p.y, acc[5]);
            p = bfpair(hvA[i].w); acc[6] = fmaf(wh, p.x, acc[6]); acc[7] = fmaf(wh, p.y, acc[7]);
        }
        #pragma unroll
        for (int i = 0; i < 4; i++) {
            evA[i] = evB[i]; anA[i] = anB[i]; hvA[i] = hvB[i];
            cB[i] = cC[i];
        }
    }

    const float rden = 1.f / fmaxf(sumw, 1e-10f);
    float a[8];
    #pragma unroll
    for (int j = 0; j < 8; j++) a[j] = acc[j] * rden;

    float s0 = 0.f;
    #pragma unroll
    for (int j = 0; j < 8; j++) s0 += a[j];
    float m0 = group4_sum(s0) * (1.f / 32.f);
    float d[8], q0 = 0.f;
    #pragma unroll
    for (int j = 0; j < 8; j++) { d[j] = a[j] - m0; q0 += d[j] * d[j]; }
    float r0 = rsqrtf(group4_sum(q0) * (1.f / 32.f) + 1e-9f);

    float4 sc0a = *(const float4*)(scale + c8);
    float4 sc0b = *(const float4*)(scale + c8 + 4);
    float4 of0a = *(const float4*)(offset + c8);
    float4 of0b = *(const float4*)(offset + c8 + 4);
    const float sc0[8] = {sc0a.x, sc0a.y, sc0a.z, sc0a.w, sc0b.x, sc0b.y, sc0b.z, sc0b.w};
    const float of0[8] = {of0a.x, of0a.y, of0a.z, of0a.w, of0b.x, of0b.y, of0b.z, of0b.w};

    uint4 nv = *(const uint4*)(nsbuf + (size_t)nid * DOUT + c8);
    float ns[8];
    { float2 p;
      p = bfpair(nv.x); ns[0] = p.x; ns[1] = p.y;
      p = bfpair(nv.y); ns[2] = p.x; ns[3] = p.y;
      p = bfpair(nv.z); ns[4] = p.x; ns[5] = p.y;
      p = bfpair(nv.w); ns[6] = p.x; ns[7] = p.y; }

    float o[8];
    #pragma unroll
    for (int j = 0; j < 8; j++)
        o[j] = 0.5f * (d[j] * sc0[j] * r0 + of0[j]) + ns[j];

    float4 oa = make_float4(o[0], o[1], o[2], o[3]);
    float4 ob = make_float4(o[4], o[5], o[6], o[7]);
    *(float4*)(out + (size_t)nid * DOUT + c8)     = oa;
    *(float4*)(out + (size_t)nid * DOUT + c8 + 4) = ob;
}

extern "C" void kernel_launch(void* const* d_in, const int* in_sizes, int n_in,
                              void* d_out, int out_size, void* d_ws, size_t ws_size,
                              hipStream_t stream) {
    const float* feat  = (const float*)d_in[0];
    const int*   erow  = (const int*)  d_in[1];
    const int*   ecol  = (const int*)  d_in[2];
    const float* eval  = (const float*)d_in[3];
    const float* W0    = (const float*)d_in[4];
    const float* b0    = (const float*)d_in[5];
    const float* W1    = (const float*)d_in[6];
    const float* b1    = (const float*)d_in[7];
    const float* att   = (const float*)d_in[8];
    const float* scale = (const float*)d_in[9];
    const float* offs  = (const float*)d_in[10];
    const int n = in_sizes[0] / DIN;
    const int E = in_sizes[2];

    unsigned short* nsbuf   = (unsigned short*)d_ws;                 // n*128
    unsigned short* h_neigh = nsbuf + (size_t)n * DOUT;              // n*128
    unsigned short* Wbf     = h_neigh + (size_t)n * DOUT;            // 32768
    float* att_self  = (float*)(Wbf + 2 * DOUT * DIN);
    float* att_neigh = att_self  + (size_t)n * NHEAD;

    kprep_w<<<16, 256, 0, stream>>>(W0, W1, (uint4*)Wbf);
    k1_mfma<<<(n + NPB - 1) / NPB, 512, 0, stream>>>(
        feat, (const uint4*)Wbf, b0, b1, att, scale, offs,
        nsbuf, h_neigh, att_self, att_neigh, n);
    k3_agg<<<(n + 15) / 16, 256, 0, stream>>>(erow, ecol, eval, att_self, att_neigh,
                                              nsbuf, h_neigh, scale, offs,
                                              (float*)d_out, n, E);
}

// Round 12
// 120.964 us; speedup vs baseline: 1.1333x; 1.1333x over previous
//
#include <hip/hip_runtime.h>
#include <hip/hip_bf16.h>

#define NHEAD 4
#define DIN 128
#define DOUT 128

typedef __attribute__((ext_vector_type(8))) short bf16x8;
typedef __attribute__((ext_vector_type(4))) float f32x4;

__device__ __forceinline__ short bfb(float f) {
    __hip_bfloat16 h = __float2bfloat16(f);
    return *reinterpret_cast<short*>(&h);
}
__device__ __forceinline__ float2 bfpair(unsigned int u) {
    float2 r;
    r.x = __uint_as_float(u << 16);
    r.y = __uint_as_float(u & 0xFFFF0000u);
    return r;
}
__device__ __forceinline__ unsigned int pk2(float lo, float hi) {
    return (unsigned int)(unsigned short)bfb(lo) |
           ((unsigned int)(unsigned short)bfb(hi) << 16);
}
__device__ __forceinline__ bf16x8 cvt8r(float4 a, float4 b) {
    bf16x8 r;
    r[0] = bfb(a.x); r[1] = bfb(a.y); r[2] = bfb(a.z); r[3] = bfb(a.w);
    r[4] = bfb(b.x); r[5] = bfb(b.y); r[6] = bfb(b.z); r[7] = bfb(b.w);
    return r;
}

// ---------------- KP: W->bf16 conversion + CSR rowptr (fused prep) ----------------
__global__ __launch_bounds__(256) void kprep(
    const float* __restrict__ W0, const float* __restrict__ W1,
    const int* __restrict__ erow, uint4* __restrict__ Wbf,
    int* __restrict__ rowptr, int n, int E)
{
    const int i = blockIdx.x * 256 + threadIdx.x;
    const int nW8 = (2 * DOUT * DIN) / 8;     // 4096
    if (i < nW8) {
        const float* s = (i < nW8 / 2) ? (W0 + (size_t)i * 8)
                                       : (W1 + (size_t)(i - nW8 / 2) * 8);
        float4 a = ((const float4*)s)[0];
        float4 b = ((const float4*)s)[1];
        Wbf[i] = make_uint4(pk2(a.x, a.y), pk2(a.z, a.w),
                            pk2(b.x, b.y), pk2(b.z, b.w));
    } else {
        int nn = i - nW8;
        if (nn <= n) {
            int lo = 0, hi = E;
            while (lo < hi) { int mid = (lo + hi) >> 1; if (erow[mid] < nn) lo = mid + 1; else hi = mid; }
            rowptr[nn] = lo;
        }
    }
}

// ---------------- K1 tile compute (4 tiles from one LDS half) ----------------
__device__ __forceinline__ void k1_tiles(
    const uint4* __restrict__ ldsbuf, int nodebase, int n,
    int col, int rg, bool selfhalf, int hd,
    const bf16x8 (&afr)[2][4],
    const float4 (&bias4)[2], const float4 (&att4)[2],
    const float4 (&sc4)[2], const float4 (&of4)[2],
    unsigned short* __restrict__ nsbuf, unsigned short* __restrict__ h_neigh,
    float* __restrict__ att_self, float* __restrict__ att_neigh)
{
    for (int tt = 0; tt < 4; tt++) {
        const int nl = tt * 16 + col;
        bf16x8 bfr[4];
        #pragma unroll
        for (int kk = 0; kk < 4; kk++) {
            uint4 u = ldsbuf[nl * 16 + ((kk * 4 + rg) ^ (col & 7))];
            *(uint4*)&bfr[kk] = u;
        }

        f32x4 acc[2] = {{0.f,0.f,0.f,0.f},{0.f,0.f,0.f,0.f}};
        #pragma unroll
        for (int kk = 0; kk < 4; kk++) {
            acc[0] = __builtin_amdgcn_mfma_f32_16x16x32_bf16(afr[0][kk], bfr[kk], acc[0], 0, 0, 0);
            acc[1] = __builtin_amdgcn_mfma_f32_16x16x32_bf16(afr[1][kk], bfr[kk], acc[1], 0, 0, 0);
        }

        const int node = nodebase + tt * 16 + col;
        const bool valid = node < n;

        float v[2][4];
        float p = 0.f;
        #pragma unroll
        for (int ct = 0; ct < 2; ct++) {
            v[ct][0] = fmaxf(acc[ct][0] + bias4[ct].x, 0.f);
            v[ct][1] = fmaxf(acc[ct][1] + bias4[ct].y, 0.f);
            v[ct][2] = fmaxf(acc[ct][2] + bias4[ct].z, 0.f);
            v[ct][3] = fmaxf(acc[ct][3] + bias4[ct].w, 0.f);
            p += v[ct][0] * att4[ct].x + v[ct][1] * att4[ct].y
               + v[ct][2] * att4[ct].z + v[ct][3] * att4[ct].w;
        }
        p += __shfl_xor(p, 16);
        p += __shfl_xor(p, 32);

        if (selfhalf) {
            float s = v[0][0]+v[0][1]+v[0][2]+v[0][3]+v[1][0]+v[1][1]+v[1][2]+v[1][3];
            s += __shfl_xor(s, 16);
            s += __shfl_xor(s, 32);
            float m = s * (1.f / 32.f);
            float q = 0.f;
            #pragma unroll
            for (int ct = 0; ct < 2; ct++)
                #pragma unroll
                for (int j = 0; j < 4; j++) { float d = v[ct][j] - m; q += d * d; }
            q += __shfl_xor(q, 16);
            q += __shfl_xor(q, 32);
            float r = rsqrtf(q * (1.f / 32.f) + 1e-9f);
            #pragma unroll
            for (int ct = 0; ct < 2; ct++) {
                float n0 = 0.5f * ((v[ct][0] - m) * sc4[ct].x * r + of4[ct].x);
                float n1 = 0.5f * ((v[ct][1] - m) * sc4[ct].y * r + of4[ct].y);
                float n2 = 0.5f * ((v[ct][2] - m) * sc4[ct].z * r + of4[ct].z);
                float n3 = 0.5f * ((v[ct][3] - m) * sc4[ct].w * r + of4[ct].w);
                ushort4 st;
                st.x = (unsigned short)bfb(n0); st.y = (unsigned short)bfb(n1);
                st.z = (unsigned short)bfb(n2); st.w = (unsigned short)bfb(n3);
                if (valid)
                    *(ushort4*)(nsbuf + (size_t)node * DOUT + hd * 32 + ct * 16 + rg * 4) = st;
            }
            if (rg == 0 && valid)
                att_self[(size_t)node * NHEAD + hd] = p > 0.f ? p : 0.2f * p;
        } else {
            #pragma unroll
            for (int ct = 0; ct < 2; ct++) {
                ushort4 st;
                st.x = (unsigned short)bfb(v[ct][0]); st.y = (unsigned short)bfb(v[ct][1]);
                st.z = (unsigned short)bfb(v[ct][2]); st.w = (unsigned short)bfb(v[ct][3]);
                if (valid)
                    *(ushort4*)(h_neigh + (size_t)node * DOUT + hd * 32 + ct * 16 + rg * 4) = st;
            }
            if (rg == 0 && valid)
                att_neigh[(size_t)node * NHEAD + hd] = p > 0.f ? p : 0.2f * p;
        }
    }
}

// ---------------- K1: double-buffered staging + MFMA dual projection ----------------
#define NPB 128

__global__ __launch_bounds__(512) void k1_mfma(
    const float* __restrict__ feat,
    const uint4* __restrict__ Wbf,
    const float* __restrict__ b0, const float* __restrict__ b1,
    const float* __restrict__ att, const float* __restrict__ scale,
    const float* __restrict__ offset,
    unsigned short* __restrict__ nsbuf, unsigned short* __restrict__ h_neigh,
    float* __restrict__ att_self, float* __restrict__ att_neigh, int n)
{
    __shared__ uint4 lds[2][64 * 16];      // 2 x 16 KB
    const int t = threadIdx.x;
    const int w = t >> 6;
    const int lane = t & 63;
    const int col = lane & 15;
    const int rg = lane >> 4;
    const bool selfhalf = (w < 4);
    const int hd = w & 3;

    bf16x8 afr[2][4];
    #pragma unroll
    for (int ct = 0; ct < 2; ct++) {
        const uint4* wr = Wbf + (size_t)(w * 32 + ct * 16 + col) * 16;
        #pragma unroll
        for (int kk = 0; kk < 4; kk++) {
            uint4 u = wr[kk * 4 + rg];
            *(uint4*)&afr[ct][kk] = u;
        }
    }
    float4 bias4[2], att4[2], sc4[2], of4[2];
    #pragma unroll
    for (int ct = 0; ct < 2; ct++) {
        int chg = w * 32 + ct * 16 + rg * 4;
        int chm = chg & 127;
        bias4[ct] = *(const float4*)((selfhalf ? b0 : b1) + chm);
        att4[ct]  = *(const float4*)(att + chg);
        sc4[ct]   = *(const float4*)(scale + 128 + chm);
        of4[ct]   = *(const float4*)(offset + 128 + chm);
    }

    const int base = blockIdx.x * NPB;

    // ---- stage half 0: load -> cvt -> LDS ----
    float4 ra[2][2];
    #pragma unroll
    for (int j = 0; j < 2; j++) {
        int li = j * 512 + t;
        int nl = li >> 4, sl = li & 15;
        int ng = base + nl; if (ng >= n) ng = n - 1;
        const float* p = feat + (size_t)ng * DIN + (sl ^ (nl & 7)) * 8;
        ra[j][0] = *(const float4*)p;
        ra[j][1] = *(const float4*)(p + 4);
    }
    #pragma unroll
    for (int j = 0; j < 2; j++) {
        bf16x8 v = cvt8r(ra[j][0], ra[j][1]);
        lds[0][j * 512 + t] = *(uint4*)&v;
    }

    // ---- issue half-1 loads early (latency hides under half-0 compute) ----
    float4 rb[2][2];
    #pragma unroll
    for (int j = 0; j < 2; j++) {
        int li = j * 512 + t;
        int nl = li >> 4, sl = li & 15;
        int ng = base + 64 + nl; if (ng >= n) ng = n - 1;
        const float* p = feat + (size_t)ng * DIN + (sl ^ (nl & 7)) * 8;
        rb[j][0] = *(const float4*)p;
        rb[j][1] = *(const float4*)(p + 4);
    }

    __syncthreads();   // LDS half 0 ready

    k1_tiles(lds[0], base, n, col, rg, selfhalf, hd, afr, bias4, att4, sc4, of4,
             nsbuf, h_neigh, att_self, att_neigh);

    // ---- write half 1 ----
    #pragma unroll
    for (int j = 0; j < 2; j++) {
        bf16x8 v = cvt8r(rb[j][0], rb[j][1]);
        lds[1][j * 512 + t] = *(uint4*)&v;
    }
    __syncthreads();   // LDS half 1 ready

    k1_tiles(lds[1], base + 64, n, col, rg, selfhalf, hd, afr, bias4, att4, sc4, of4,
             nsbuf, h_neigh, att_self, att_neigh);
}

// ---------------- K3: fused softmax + weighted aggregate + agg LN + combine ----------
// 256 threads = 16 nodes/block, 16 lanes/node, 8 channels/thread (uint4 gather).
// 2-deep pipeline (stage B issued while consuming A), cols one batch further ahead.
__device__ __forceinline__ float group4_sum(float v) {
    v += __shfl_xor(v, 1);
    v += __shfl_xor(v, 2);
    return v;
}

__global__ __launch_bounds__(256) void k3_agg(
    const int* __restrict__ rowptr, const int* __restrict__ ecol,
    const float* __restrict__ eval,
    const float* __restrict__ att_self, const float* __restrict__ att_neigh,
    const unsigned short* __restrict__ nsbuf, const unsigned short* __restrict__ h_neigh,
    const float* __restrict__ scale, const float* __restrict__ offset,
    float* __restrict__ out, int n_nodes)
{
    const int t = threadIdx.x;
    const int g = t >> 4;
    const int lane = t & 15;
    const int nid = blockIdx.x * 16 + g;
    if (nid >= n_nodes) return;
    const int head = lane >> 2;
    const int c8 = lane * 8;

    const int start = rowptr[nid], end = rowptr[nid + 1];
    const float as = att_self[(size_t)nid * NHEAD + head];

    float acc[8];
    #pragma unroll
    for (int j = 0; j < 8; j++) acc[j] = 0.f;
    float sumw = 0.f;

    float evA[4], anA[4];
    uint4 hvA[4];
    int cB[4];
    {
        int cA[4];
        #pragma unroll
        for (int i = 0; i < 4; i++) cA[i] = (start + i     < end) ? ecol[start + i]     : 0;
        #pragma unroll
        for (int i = 0; i < 4; i++) cB[i] = (start + 4 + i < end) ? ecol[start + 4 + i] : 0;
        #pragma unroll
        for (int i = 0; i < 4; i++) {
            evA[i] = (start + i < end) ? eval[start + i] : 0.f;
            anA[i] = att_neigh[(size_t)cA[i] * NHEAD + head];
            hvA[i] = *(const uint4*)(h_neigh + (size_t)cA[i] * DOUT + c8);
        }
    }

    for (int e = start; e < end; e += 4) {
        float evB[4], anB[4];
        uint4 hvB[4];
        #pragma unroll
        for (int i = 0; i < 4; i++) {
            evB[i] = (e + 4 + i < end) ? eval[e + 4 + i] : 0.f;
            anB[i] = att_neigh[(size_t)cB[i] * NHEAD + head];
            hvB[i] = *(const uint4*)(h_neigh + (size_t)cB[i] * DOUT + c8);
        }
        int cC[4];
        #pragma unroll
        for (int i = 0; i < 4; i++)
            cC[i] = (e + 8 + i < end) ? ecol[e + 8 + i] : 0;

        #pragma unroll
        for (int i = 0; i < 4; i++) {
            float wh = __expf(as + anA[i]) * evA[i];
            sumw += wh;
            float2 p;
            p = bfpair(hvA[i].x); acc[0] = fmaf(wh, p.x, acc[0]); acc[1] = fmaf(wh, p.y, acc[1]);
            p = bfpair(hvA[i].y); acc[2] = fmaf(wh, p.x, acc[2]); acc[3] = fmaf(wh, p.y, acc[3]);
            p = bfpair(hvA[i].z); acc[4] = fmaf(wh, p.x, acc[4]); acc[5] = fmaf(wh, p.y, acc[5]);
            p = bfpair(hvA[i].w); acc[6] = fmaf(wh, p.x, acc[6]); acc[7] = fmaf(wh, p.y, acc[7]);
        }
        #pragma unroll
        for (int i = 0; i < 4; i++) {
            evA[i] = evB[i]; anA[i] = anB[i]; hvA[i] = hvB[i];
            cB[i] = cC[i];
        }
    }

    const float rden = 1.f / fmaxf(sumw, 1e-10f);
    float a[8];
    #pragma unroll
    for (int j = 0; j < 8; j++) a[j] = acc[j] * rden;

    float s0 = 0.f;
    #pragma unroll
    for (int j = 0; j < 8; j++) s0 += a[j];
    float m0 = group4_sum(s0) * (1.f / 32.f);
    float d[8], q0 = 0.f;
    #pragma unroll
    for (int j = 0; j < 8; j++) { d[j] = a[j] - m0; q0 += d[j] * d[j]; }
    float r0 = rsqrtf(group4_sum(q0) * (1.f / 32.f) + 1e-9f);

    float4 sc0a = *(const float4*)(scale + c8);
    float4 sc0b = *(const float4*)(scale + c8 + 4);
    float4 of0a = *(const float4*)(offset + c8);
    float4 of0b = *(const float4*)(offset + c8 + 4);
    const float sc0[8] = {sc0a.x, sc0a.y, sc0a.z, sc0a.w, sc0b.x, sc0b.y, sc0b.z, sc0b.w};
    const float of0[8] = {of0a.x, of0a.y, of0a.z, of0a.w, of0b.x, of0b.y, of0b.z, of0b.w};

    uint4 nv = *(const uint4*)(nsbuf + (size_t)nid * DOUT + c8);
    float ns[8];
    { float2 p;
      p = bfpair(nv.x); ns[0] = p.x; ns[1] = p.y;
      p = bfpair(nv.y); ns[2] = p.x; ns[3] = p.y;
      p = bfpair(nv.z); ns[4] = p.x; ns[5] = p.y;
      p = bfpair(nv.w); ns[6] = p.x; ns[7] = p.y; }

    float o[8];
    #pragma unroll
    for (int j = 0; j < 8; j++)
        o[j] = 0.5f * (d[j] * sc0[j] * r0 + of0[j]) + ns[j];

    float4 oa = make_float4(o[0], o[1], o[2], o[3]);
    float4 ob = make_float4(o[4], o[5], o[6], o[7]);
    *(float4*)(out + (size_t)nid * DOUT + c8)     = oa;
    *(float4*)(out + (size_t)nid * DOUT + c8 + 4) = ob;
}

extern "C" void kernel_launch(void* const* d_in, const int* in_sizes, int n_in,
                              void* d_out, int out_size, void* d_ws, size_t ws_size,
                              hipStream_t stream) {
    const float* feat  = (const float*)d_in[0];
    const int*   erow  = (const int*)  d_in[1];
    const int*   ecol  = (const int*)  d_in[2];
    const float* eval  = (const float*)d_in[3];
    const float* W0    = (const float*)d_in[4];
    const float* b0    = (const float*)d_in[5];
    const float* W1    = (const float*)d_in[6];
    const float* b1    = (const float*)d_in[7];
    const float* att   = (const float*)d_in[8];
    const float* scale = (const float*)d_in[9];
    const float* offs  = (const float*)d_in[10];
    const int n = in_sizes[0] / DIN;
    const int E = in_sizes[2];

    unsigned short* nsbuf   = (unsigned short*)d_ws;                 // n*128
    unsigned short* h_neigh = nsbuf + (size_t)n * DOUT;              // n*128
    unsigned short* Wbf     = h_neigh + (size_t)n * DOUT;            // 32768
    float* att_self  = (float*)(Wbf + 2 * DOUT * DIN);
    float* att_neigh = att_self  + (size_t)n * NHEAD;
    int*   rowptr    = (int*)(att_neigh + (size_t)n * NHEAD);

    const int nW8 = (2 * DOUT * DIN) / 8;
    kprep<<<(nW8 + n + 1 + 255) / 256, 256, 0, stream>>>(
        W0, W1, erow, (uint4*)Wbf, rowptr, n, E);
    k1_mfma<<<(n + NPB - 1) / NPB, 512, 0, stream>>>(
        feat, (const uint4*)Wbf, b0, b1, att, scale, offs,
        nsbuf, h_neigh, att_self, att_neigh, n);
    k3_agg<<<(n + 15) / 16, 256, 0, stream>>>(rowptr, ecol, eval, att_self, att_neigh,
                                              nsbuf, h_neigh, scale, offs,
                                              (float*)d_out, n);
}

// Round 13
// 101.671 us; speedup vs baseline: 1.3484x; 1.1898x over previous
//
#include <hip/hip_runtime.h>
#include <hip/hip_bf16.h>

#define NHEAD 4
#define DIN 128
#define DOUT 128

typedef __attribute__((ext_vector_type(8))) short bf16x8;
typedef __attribute__((ext_vector_type(4))) float f32x4;

__device__ __forceinline__ short bfb(float f) {
    __hip_bfloat16 h = __float2bfloat16(f);
    return *reinterpret_cast<short*>(&h);
}
__device__ __forceinline__ float2 bfpair(unsigned int u) {
    float2 r;
    r.x = __uint_as_float(u << 16);
    r.y = __uint_as_float(u & 0xFFFF0000u);
    return r;
}
__device__ __forceinline__ unsigned int pk2(float lo, float hi) {
    return (unsigned int)(unsigned short)bfb(lo) |
           ((unsigned int)(unsigned short)bfb(hi) << 16);
}
__device__ __forceinline__ bf16x8 cvt8r(float4 a, float4 b) {
    bf16x8 r;
    r[0] = bfb(a.x); r[1] = bfb(a.y); r[2] = bfb(a.z); r[3] = bfb(a.w);
    r[4] = bfb(b.x); r[5] = bfb(b.y); r[6] = bfb(b.z); r[7] = bfb(b.w);
    return r;
}

// ---------------- KP: W -> bf16 (tiny) ----------------
__global__ __launch_bounds__(256) void kprep_w(
    const float* __restrict__ W0, const float* __restrict__ W1,
    uint4* __restrict__ Wbf)
{
    const int i = blockIdx.x * 256 + threadIdx.x;
    const int nW8 = (2 * DOUT * DIN) / 8;     // 4096
    if (i >= nW8) return;
    const float* s = (i < nW8 / 2) ? (W0 + (size_t)i * 8)
                                   : (W1 + (size_t)(i - nW8 / 2) * 8);
    float4 a = ((const float4*)s)[0];
    float4 b = ((const float4*)s)[1];
    Wbf[i] = make_uint4(pk2(a.x, a.y), pk2(a.z, a.w),
                        pk2(b.x, b.y), pk2(b.z, b.w));
}

// ---------------- K1 tile compute (4 tiles from one LDS half) ----------------
// self waves -> nsbuf (0.5*LN(h_self) bf16) + att_self
// neigh waves -> hq (uint8, per-head max scale) + ascl (packed {att, scale} float2)
__device__ __forceinline__ void k1_tiles(
    const uint4* __restrict__ ldsbuf, int nodebase, int n,
    int col, int rg, bool selfhalf, int hd,
    const bf16x8 (&afr)[2][4],
    const float4 (&bias4)[2], const float4 (&att4)[2],
    const float4 (&sc4)[2], const float4 (&of4)[2],
    unsigned short* __restrict__ nsbuf, unsigned char* __restrict__ hq,
    float* __restrict__ att_self, float* __restrict__ ascl)
{
    for (int tt = 0; tt < 4; tt++) {
        const int nl = tt * 16 + col;
        bf16x8 bfr[4];
        #pragma unroll
        for (int kk = 0; kk < 4; kk++) {
            uint4 u = ldsbuf[nl * 16 + ((kk * 4 + rg) ^ (col & 7))];
            *(uint4*)&bfr[kk] = u;
        }

        f32x4 acc[2] = {{0.f,0.f,0.f,0.f},{0.f,0.f,0.f,0.f}};
        #pragma unroll
        for (int kk = 0; kk < 4; kk++) {
            acc[0] = __builtin_amdgcn_mfma_f32_16x16x32_bf16(afr[0][kk], bfr[kk], acc[0], 0, 0, 0);
            acc[1] = __builtin_amdgcn_mfma_f32_16x16x32_bf16(afr[1][kk], bfr[kk], acc[1], 0, 0, 0);
        }

        const int node = nodebase + tt * 16 + col;
        const bool valid = node < n;

        float v[2][4];
        float p = 0.f;
        #pragma unroll
        for (int ct = 0; ct < 2; ct++) {
            v[ct][0] = fmaxf(acc[ct][0] + bias4[ct].x, 0.f);
            v[ct][1] = fmaxf(acc[ct][1] + bias4[ct].y, 0.f);
            v[ct][2] = fmaxf(acc[ct][2] + bias4[ct].z, 0.f);
            v[ct][3] = fmaxf(acc[ct][3] + bias4[ct].w, 0.f);
            p += v[ct][0] * att4[ct].x + v[ct][1] * att4[ct].y
               + v[ct][2] * att4[ct].z + v[ct][3] * att4[ct].w;
        }
        p += __shfl_xor(p, 16);
        p += __shfl_xor(p, 32);

        if (selfhalf) {
            float s = v[0][0]+v[0][1]+v[0][2]+v[0][3]+v[1][0]+v[1][1]+v[1][2]+v[1][3];
            s += __shfl_xor(s, 16);
            s += __shfl_xor(s, 32);
            float m = s * (1.f / 32.f);
            float q = 0.f;
            #pragma unroll
            for (int ct = 0; ct < 2; ct++)
                #pragma unroll
                for (int j = 0; j < 4; j++) { float d = v[ct][j] - m; q += d * d; }
            q += __shfl_xor(q, 16);
            q += __shfl_xor(q, 32);
            float r = rsqrtf(q * (1.f / 32.f) + 1e-9f);
            #pragma unroll
            for (int ct = 0; ct < 2; ct++) {
                float n0 = 0.5f * ((v[ct][0] - m) * sc4[ct].x * r + of4[ct].x);
                float n1 = 0.5f * ((v[ct][1] - m) * sc4[ct].y * r + of4[ct].y);
                float n2 = 0.5f * ((v[ct][2] - m) * sc4[ct].z * r + of4[ct].z);
                float n3 = 0.5f * ((v[ct][3] - m) * sc4[ct].w * r + of4[ct].w);
                ushort4 st;
                st.x = (unsigned short)bfb(n0); st.y = (unsigned short)bfb(n1);
                st.z = (unsigned short)bfb(n2); st.w = (unsigned short)bfb(n3);
                if (valid)
                    *(ushort4*)(nsbuf + (size_t)node * DOUT + hd * 32 + ct * 16 + rg * 4) = st;
            }
            if (rg == 0 && valid)
                att_self[(size_t)node * NHEAD + hd] = p > 0.f ? p : 0.2f * p;
        } else {
            // per-(node,head) max over 32 channels: local 8, then across rg groups
            float mh = 0.f;
            #pragma unroll
            for (int ct = 0; ct < 2; ct++)
                #pragma unroll
                for (int j = 0; j < 4; j++) mh = fmaxf(mh, v[ct][j]);
            mh = fmaxf(mh, __shfl_xor(mh, 16));
            mh = fmaxf(mh, __shfl_xor(mh, 32));
            const float rsc = mh > 0.f ? 255.f / mh : 0.f;
            #pragma unroll
            for (int ct = 0; ct < 2; ct++) {
                unsigned int u = 0;
                u |= (unsigned int)(v[ct][0] * rsc + 0.5f);
                u |= (unsigned int)(v[ct][1] * rsc + 0.5f) << 8;
                u |= (unsigned int)(v[ct][2] * rsc + 0.5f) << 16;
                u |= (unsigned int)(v[ct][3] * rsc + 0.5f) << 24;
                if (valid)
                    *(unsigned int*)(hq + (size_t)node * DOUT + hd * 32 + ct * 16 + rg * 4) = u;
            }
            if (rg == 0 && valid) {
                float2 o;
                o.x = p > 0.f ? p : 0.2f * p;     // att_neigh logit
                o.y = mh * (1.f / 255.f);          // dequant scale
                *(float2*)(ascl + (size_t)node * 8 + hd * 2) = o;
            }
        }
    }
}

// ---------------- K1: double-buffered staging + MFMA + fused rowptr tail ------------
#define NPB 128

__global__ __launch_bounds__(512) void k1_mfma(
    const float* __restrict__ feat,
    const uint4* __restrict__ Wbf,
    const float* __restrict__ b0, const float* __restrict__ b1,
    const float* __restrict__ att, const float* __restrict__ scale,
    const float* __restrict__ offset,
    unsigned short* __restrict__ nsbuf, unsigned char* __restrict__ hq,
    float* __restrict__ att_self, float* __restrict__ ascl,
    const int* __restrict__ erow, int* __restrict__ rowptr,
    int n, int E, int NB1)
{
    __shared__ uint4 lds[2][64 * 16];      // 2 x 16 KB
    const int t = threadIdx.x;

    // tail blocks: CSR rowptr by binary search (overlaps with MFMA blocks)
    if ((int)blockIdx.x >= NB1) {
        int idx = ((int)blockIdx.x - NB1) * 512 + t;
        if (idx <= n) {
            int lo = 0, hi = E;
            while (lo < hi) { int mid = (lo + hi) >> 1; if (erow[mid] < idx) lo = mid + 1; else hi = mid; }
            rowptr[idx] = lo;
        }
        return;
    }

    const int w = t >> 6;
    const int lane = t & 63;
    const int col = lane & 15;
    const int rg = lane >> 4;
    const bool selfhalf = (w < 4);
    const int hd = w & 3;

    bf16x8 afr[2][4];
    #pragma unroll
    for (int ct = 0; ct < 2; ct++) {
        const uint4* wr = Wbf + (size_t)(w * 32 + ct * 16 + col) * 16;
        #pragma unroll
        for (int kk = 0; kk < 4; kk++) {
            uint4 u = wr[kk * 4 + rg];
            *(uint4*)&afr[ct][kk] = u;
        }
    }
    float4 bias4[2], att4[2], sc4[2], of4[2];
    #pragma unroll
    for (int ct = 0; ct < 2; ct++) {
        int chg = w * 32 + ct * 16 + rg * 4;
        int chm = chg & 127;
        bias4[ct] = *(const float4*)((selfhalf ? b0 : b1) + chm);
        att4[ct]  = *(const float4*)(att + chg);
        sc4[ct]   = *(const float4*)(scale + 128 + chm);
        of4[ct]   = *(const float4*)(offset + 128 + chm);
    }

    const int base = blockIdx.x * NPB;

    float4 ra[2][2];
    #pragma unroll
    for (int j = 0; j < 2; j++) {
        int li = j * 512 + t;
        int nl = li >> 4, sl = li & 15;
        int ng = base + nl; if (ng >= n) ng = n - 1;
        const float* p = feat + (size_t)ng * DIN + (sl ^ (nl & 7)) * 8;
        ra[j][0] = *(const float4*)p;
        ra[j][1] = *(const float4*)(p + 4);
    }
    #pragma unroll
    for (int j = 0; j < 2; j++) {
        bf16x8 v = cvt8r(ra[j][0], ra[j][1]);
        lds[0][j * 512 + t] = *(uint4*)&v;
    }

    float4 rb[2][2];
    #pragma unroll
    for (int j = 0; j < 2; j++) {
        int li = j * 512 + t;
        int nl = li >> 4, sl = li & 15;
        int ng = base + 64 + nl; if (ng >= n) ng = n - 1;
        const float* p = feat + (size_t)ng * DIN + (sl ^ (nl & 7)) * 8;
        rb[j][0] = *(const float4*)p;
        rb[j][1] = *(const float4*)(p + 4);
    }

    __syncthreads();

    k1_tiles(lds[0], base, n, col, rg, selfhalf, hd, afr, bias4, att4, sc4, of4,
             nsbuf, hq, att_self, ascl);

    #pragma unroll
    for (int j = 0; j < 2; j++) {
        bf16x8 v = cvt8r(rb[j][0], rb[j][1]);
        lds[1][j * 512 + t] = *(uint4*)&v;
    }
    __syncthreads();

    k1_tiles(lds[1], base + 64, n, col, rg, selfhalf, hd, afr, bias4, att4, sc4, of4,
             nsbuf, hq, att_self, ascl);
}

// ---------------- K3: softmax + uint8 weighted aggregate + agg LN + combine ---------
// 256 threads = 16 nodes/block, 16 lanes/node, 8 channels/thread (uint2 gather).
// 2-deep pipeline. Dequant scale folded into the edge weight (wq = wh * scale).
__device__ __forceinline__ float group4_sum(float v) {
    v += __shfl_xor(v, 1);
    v += __shfl_xor(v, 2);
    return v;
}

__global__ __launch_bounds__(256) void k3_agg(
    const int* __restrict__ rowptr, const int* __restrict__ ecol,
    const float* __restrict__ eval,
    const float* __restrict__ att_self, const float* __restrict__ ascl,
    const unsigned short* __restrict__ nsbuf, const unsigned char* __restrict__ hq,
    const float* __restrict__ scale, const float* __restrict__ offset,
    float* __restrict__ out, int n_nodes)
{
    const int t = threadIdx.x;
    const int g = t >> 4;
    const int lane = t & 15;
    const int nid = blockIdx.x * 16 + g;
    if (nid >= n_nodes) return;
    const int head = lane >> 2;
    const int c8 = lane * 8;

    const int start = rowptr[nid], end = rowptr[nid + 1];
    const float as = att_self[(size_t)nid * NHEAD + head];

    float acc[8];
    #pragma unroll
    for (int j = 0; j < 8; j++) acc[j] = 0.f;
    float sumw = 0.f;

    float evA[4];
    float2 ascA[4];
    uint2 hqA[4];
    int cB[4];
    {
        int cA[4];
        #pragma unroll
        for (int i = 0; i < 4; i++) cA[i] = (start + i     < end) ? ecol[start + i]     : 0;
        #pragma unroll
        for (int i = 0; i < 4; i++) cB[i] = (start + 4 + i < end) ? ecol[start + 4 + i] : 0;
        #pragma unroll
        for (int i = 0; i < 4; i++) {
            evA[i]  = (start + i < end) ? eval[start + i] : 0.f;
            ascA[i] = *(const float2*)(ascl + (size_t)cA[i] * 8 + head * 2);
            hqA[i]  = *(const uint2*)(hq + (size_t)cA[i] * DOUT + c8);
        }
    }

    for (int e = start; e < end; e += 4) {
        float evB[4];
        float2 ascB[4];
        uint2 hqB[4];
        #pragma unroll
        for (int i = 0; i < 4; i++) {
            evB[i]  = (e + 4 + i < end) ? eval[e + 4 + i] : 0.f;
            ascB[i] = *(const float2*)(ascl + (size_t)cB[i] * 8 + head * 2);
            hqB[i]  = *(const uint2*)(hq + (size_t)cB[i] * DOUT + c8);
        }
        int cC[4];
        #pragma unroll
        for (int i = 0; i < 4; i++)
            cC[i] = (e + 8 + i < end) ? ecol[e + 8 + i] : 0;

        #pragma unroll
        for (int i = 0; i < 4; i++) {
            float wh = __expf(as + ascA[i].x) * evA[i];
            sumw += wh;
            float wq = wh * ascA[i].y;
            unsigned int hx = hqA[i].x, hy = hqA[i].y;
            acc[0] = fmaf(wq, (float)(hx & 255u),         acc[0]);
            acc[1] = fmaf(wq, (float)((hx >> 8) & 255u),  acc[1]);
            acc[2] = fmaf(wq, (float)((hx >> 16) & 255u), acc[2]);
            acc[3] = fmaf(wq, (float)(hx >> 24),          acc[3]);
            acc[4] = fmaf(wq, (float)(hy & 255u),         acc[4]);
            acc[5] = fmaf(wq, (float)((hy >> 8) & 255u),  acc[5]);
            acc[6] = fmaf(wq, (float)((hy >> 16) & 255u), acc[6]);
            acc[7] = fmaf(wq, (float)(hy >> 24),          acc[7]);
        }
        #pragma unroll
        for (int i = 0; i < 4; i++) {
            evA[i] = evB[i]; ascA[i] = ascB[i]; hqA[i] = hqB[i];
            cB[i] = cC[i];
        }
    }

    const float rden = 1.f / fmaxf(sumw, 1e-10f);
    float a[8];
    #pragma unroll
    for (int j = 0; j < 8; j++) a[j] = acc[j] * rden;

    float s0 = 0.f;
    #pragma unroll
    for (int j = 0; j < 8; j++) s0 += a[j];
    float m0 = group4_sum(s0) * (1.f / 32.f);
    float d[8], q0 = 0.f;
    #pragma unroll
    for (int j = 0; j < 8; j++) { d[j] = a[j] - m0; q0 += d[j] * d[j]; }
    float r0 = rsqrtf(group4_sum(q0) * (1.f / 32.f) + 1e-9f);

    float4 sc0a = *(const float4*)(scale + c8);
    float4 sc0b = *(const float4*)(scale + c8 + 4);
    float4 of0a = *(const float4*)(offset + c8);
    float4 of0b = *(const float4*)(offset + c8 + 4);
    const float sc0[8] = {sc0a.x, sc0a.y, sc0a.z, sc0a.w, sc0b.x, sc0b.y, sc0b.z, sc0b.w};
    const float of0[8] = {of0a.x, of0a.y, of0a.z, of0a.w, of0b.x, of0b.y, of0b.z, of0b.w};

    uint4 nv = *(const uint4*)(nsbuf + (size_t)nid * DOUT + c8);
    float ns[8];
    { float2 p;
      p = bfpair(nv.x); ns[0] = p.x; ns[1] = p.y;
      p = bfpair(nv.y); ns[2] = p.x; ns[3] = p.y;
      p = bfpair(nv.z); ns[4] = p.x; ns[5] = p.y;
      p = bfpair(nv.w); ns[6] = p.x; ns[7] = p.y; }

    float o[8];
    #pragma unroll
    for (int j = 0; j < 8; j++)
        o[j] = 0.5f * (d[j] * sc0[j] * r0 + of0[j]) + ns[j];

    float4 oa = make_float4(o[0], o[1], o[2], o[3]);
    float4 ob = make_float4(o[4], o[5], o[6], o[7]);
    *(float4*)(out + (size_t)nid * DOUT + c8)     = oa;
    *(float4*)(out + (size_t)nid * DOUT + c8 + 4) = ob;
}

extern "C" void kernel_launch(void* const* d_in, const int* in_sizes, int n_in,
                              void* d_out, int out_size, void* d_ws, size_t ws_size,
                              hipStream_t stream) {
    const float* feat  = (const float*)d_in[0];
    const int*   erow  = (const int*)  d_in[1];
    const int*   ecol  = (const int*)  d_in[2];
    const float* eval  = (const float*)d_in[3];
    const float* W0    = (const float*)d_in[4];
    const float* b0    = (const float*)d_in[5];
    const float* W1    = (const float*)d_in[6];
    const float* b1    = (const float*)d_in[7];
    const float* att   = (const float*)d_in[8];
    const float* scale = (const float*)d_in[9];
    const float* offs  = (const float*)d_in[10];
    const int n = in_sizes[0] / DIN;
    const int E = in_sizes[2];

    unsigned short* nsbuf = (unsigned short*)d_ws;                       // n*128 bf16
    unsigned char*  hq    = (unsigned char*)(nsbuf + (size_t)n * DOUT);  // n*128 u8
    unsigned short* Wbf   = (unsigned short*)(hq + (size_t)n * DOUT);    // 32768 bf16
    float* ascl     = (float*)(Wbf + 2 * DOUT * DIN);                    // n*8 {att,scale}
    float* att_self = ascl + (size_t)n * 8;                              // n*4
    int*   rowptr   = (int*)(att_self + (size_t)n * NHEAD);              // n+1

    const int NB1 = (n + NPB - 1) / NPB;
    const int NBr = (n + 512) / 512;     // blocks covering n+1 rowptr entries

    kprep_w<<<16, 256, 0, stream>>>(W0, W1, (uint4*)Wbf);
    k1_mfma<<<NB1 + NBr, 512, 0, stream>>>(
        feat, (const uint4*)Wbf, b0, b1, att, scale, offs,
        nsbuf, hq, att_self, ascl, erow, rowptr, n, E, NB1);
    k3_agg<<<(n + 15) / 16, 256, 0, stream>>>(rowptr, ecol, eval, att_self, ascl,
                                              nsbuf, hq, scale, offs,
                                              (float*)d_out, n);
}